// Round 5
// baseline (331.875 us; speedup 1.0000x reference)
//
#include <hip/hip_runtime.h>

#define N_NODES 10000
#define NEDGE 160000
#define NB 80000  /* N_NODES*BATCH */
#define EPAD (NEDGE + 8 * N_NODES) /* padded edge capacity per support */

typedef unsigned int u32;
typedef unsigned short u16;
typedef __attribute__((ext_vector_type(8))) short short8;
typedef __attribute__((ext_vector_type(4))) float float4v;

__device__ __forceinline__ u16 f2bf(float f) {
    u32 u = __float_as_uint(f);
    return (u16)((u + 0x7fffu + ((u >> 16) & 1u)) >> 16);
}
__device__ __forceinline__ float lo16(u32 u) { return __uint_as_float(u << 16); }
__device__ __forceinline__ float hi16(u32 u) { return __uint_as_float(u & 0xffff0000u); }
__device__ __forceinline__ u32 pack2(float a, float b) {
    return (u32)f2bf(a) | (((u32)f2bf(b)) << 16);
}
__device__ __forceinline__ float fast_tanh(float v) {
    return 1.f - 2.f / (__expf(2.f * v) + 1.f);
}

static const size_t SLAB = (size_t)NB * 64;  // u16 elems per 64-wide slab

// ---------------- prep+count: transpose + bpack12 + bpackP + degree count -----------
__global__ __launch_bounds__(256) void prepcount_kernel(
    const float2* __restrict__ y, u32* __restrict__ X0,
    const float* __restrict__ W_lat, const float* __restrict__ W_units,
    u16* __restrict__ bpk12, const float* __restrict__ W_final, u16* __restrict__ bpkP,
    const int* __restrict__ rows, const int* __restrict__ cols, int* __restrict__ cnt) {
    int b = blockIdx.x, t = threadIdx.x;
    if (b < 10000) {
        int idx = b * 256 + t;  // NB*32 outputs exactly
        int fh = idx & 31;
        int rb = idx >> 5;
        int bb = rb & 7;
        int n = rb >> 3;
        float2 v = y[((size_t)bb * N_NODES + n) * 32 + fh];
        X0[idx] = pack2(v.x, v.y);
    } else if (b < 10240) {
        // fused bpack: K=320 (k=m*64+f, wrow=f*5+m), NOUT=192 (0..63 lat, 64..191 units)
        int idx = (b - 10000) * 256 + t;  // < 61440
        int j = idx & 7;
        int lane = (idx >> 3) & 63;
        int rest = idx >> 9;
        int ct = rest % 12;
        int ks = rest / 12;
        int k = ks * 32 + (lane >> 4) * 8 + j;
        int col = ct * 16 + (lane & 15);
        int wrow = (k % 64) * 5 + (k / 64);
        float v = (col < 64) ? W_lat[wrow * 64 + col] : W_units[wrow * 128 + (col - 64)];
        bpk12[idx] = f2bf(v);
    } else if (b < 10400) {
        // bpackP: K=128, NOUT=320; slot0 = W[:,0]-W[:,2]-W[:,4], slot m>=1 = W[:,m]
        int idx = (b - 10240) * 256 + t;  // < 40960
        int j8 = idx & 7;
        int lane = (idx >> 3) & 63;
        int rest = idx >> 9;
        int ct = rest % 20;
        int ks = rest / 20;
        int k = ks * 32 + (lane >> 4) * 8 + j8;
        int col = ct * 16 + (lane & 15);
        int slot = col >> 6, j = col & 63;
        float v;
        if (slot == 0)
            v = W_final[(k * 5 + 0) * 64 + j] - W_final[(k * 5 + 2) * 64 + j] -
                W_final[(k * 5 + 4) * 64 + j];
        else
            v = W_final[(k * 5 + slot) * 64 + j];
        bpkP[idx] = f2bf(v);
    } else {
        int e = (b - 10400) * 256 + t;  // 625*256 == NEDGE exactly
        atomicAdd(&cnt[cols[e]], 1);            // support1: dst=cols
        atomicAdd(&cnt[N_NODES + rows[e]], 1);  // support2: dst=rows
    }
}

// 80 blocks: per-chunk sums of PADDED degrees (rows padded to multiple of 8)
__global__ void blocksum_kernel(const int* __restrict__ cnt, int* __restrict__ bsums) {
    __shared__ int red[4];
    int arr = blockIdx.x / 40;
    int c = blockIdx.x % 40;
    int idx = c * 256 + threadIdx.x;
    int v = (idx < N_NODES) ? ((cnt[arr * N_NODES + idx] + 7) & ~7) : 0;
#pragma unroll
    for (int off = 32; off; off >>= 1) v += __shfl_down(v, off, 64);
    int wv = threadIdx.x >> 6, ln = threadIdx.x & 63;
    if (ln == 0) red[wv] = v;
    __syncthreads();
    if (threadIdx.x == 0) bsums[blockIdx.x] = red[0] + red[1] + red[2] + red[3];
}

// 80 blocks: local scan + serial prefix over chunk sums -> padded rowptr + cursor
__global__ void scanapply_kernel(int* __restrict__ cnt, const int* __restrict__ bsums,
                                 int* __restrict__ rowptr1, int* __restrict__ rowptr2) {
    __shared__ int lds[256];
    int arr = blockIdx.x / 40;
    int c = blockIdx.x % 40;
    int base = 0;
    for (int i = 0; i < c; i++) base += bsums[arr * 40 + i];  // 40-deep serial, L2-hot
    int idx = c * 256 + threadIdx.x;
    bool ok = idx < N_NODES;
    int v = ok ? ((cnt[arr * N_NODES + idx] + 7) & ~7) : 0;
    int t = threadIdx.x;
    lds[t] = v;
    __syncthreads();
    for (int off = 1; off < 256; off <<= 1) {
        int add = (t >= off) ? lds[t - off] : 0;
        __syncthreads();
        lds[t] += add;
        __syncthreads();
    }
    int excl = lds[t] - v + base;
    if (ok) {
        int* rp = arr ? rowptr2 : rowptr1;
        rp[idx] = excl;
        cnt[arr * N_NODES + idx] = excl;  // cursor (actual edges fill from padded start)
    }
    if (c == 39 && t == 255) {
        // grand total (padded) = base + inclusive total of last chunk
        (arr ? rowptr2 : rowptr1)[N_NODES] = base + lds[255];
    }
}

__global__ void scatter_kernel(const int* __restrict__ rows, const int* __restrict__ cols,
                               const float* __restrict__ w1, const float* __restrict__ w2,
                               int* __restrict__ cur1, int* __restrict__ cur2,
                               int2* __restrict__ edges1, int2* __restrict__ edges2) {
    int e = blockIdx.x * 256 + threadIdx.x;
    if (e < NEDGE) {
        int r = rows[e], c = cols[e];
        int p1 = atomicAdd(&cur1[c], 1);
        edges1[p1] = make_int2(r, __float_as_int(w1[e]));
        int p2 = atomicAdd(&cur2[r], 1);
        edges2[p2] = make_int2(c, __float_as_int(w2[e]));
    }
}

// ---------------- SpMM gather: XCD-sliced, 16 lanes/row (split-K, halved chain) ----
// Wave = 4 row-groups x 16 lanes; each 16-lane group owns ONE destination row's 128B
// batch-slice (slice = blockIdx%8 -> one XCD; per-XCD gather set 2.56MB -> L2).
// The 16 lanes split into two 8-lane subgroups h=0/1 processing alternating 8-edge
// chunks -> sequential chunk depth halves; partials combined via shfl_xor(.,8).
// Next-chunk edge data is prefetched so the edge load is off the critical path.
__device__ __forceinline__ void gacc(float* acc, float w, uint4 u) {
    acc[0] += w * lo16(u.x); acc[1] += w * hi16(u.x);
    acc[2] += w * lo16(u.y); acc[3] += w * hi16(u.y);
    acc[4] += w * lo16(u.z); acc[5] += w * hi16(u.z);
    acc[6] += w * lo16(u.w); acc[7] += w * hi16(u.w);
}

__device__ __forceinline__ void gather_sliced(const u32* __restrict__ Xin,
                                              const int* __restrict__ rp,
                                              const int2* __restrict__ eg,
                                              int row, int su, int l, int h,
                                              float* acc) {
    int e = rp[row] + h * 8 + l;
    int e1 = rp[row + 1];
    int2 me = make_int2(0, 0);
    if (e < e1) me = eg[e];
    while (__ballot(e < e1)) {
        int en = e + 16;
        int2 men = make_int2(0, 0);
        if (en < e1) men = eg[en];
#pragma unroll
        for (int j = 0; j < 8; j++) {
            int s = __shfl(me.x, j, 8);
            float w = __int_as_float(__shfl(me.y, j, 8));
            uint4 u = *(const uint4*)(Xin + (size_t)s * 256 + su + l * 4);
            gacc(acc, w, u);
        }
        e = en;
        me = men;
    }
}

__global__ __launch_bounds__(256) void spmm2_kernel(
    const u32* __restrict__ XinA, const u32* __restrict__ XprevA, u32* __restrict__ XoutA,
    const u32* __restrict__ XinB, const u32* __restrict__ XprevB, u32* __restrict__ XoutB,
    const int* __restrict__ rowptr1, const int2* __restrict__ edges1,
    const int* __restrict__ rowptr2, const int2* __restrict__ edges2,
    float alpha, float beta) {
    int t = threadIdx.x;
    int lane = t & 63;
    int g = lane >> 4;         // 4 row-groups per wave
    int l16 = lane & 15;
    int h = l16 >> 3, l = l16 & 7;
    int slice = blockIdx.x & 7;            // -> XCD (round-robin dispatch)
    int chunk = blockIdx.x >> 3;           // 1250 chunks x 16 rows = 20000
    int su = slice * 32;                   // u32 offset of this batch-slice in a row
    int v = chunk * 16 + (t >> 6) * 4 + g; // 0..19999 exactly
    bool hB = v >= N_NODES;
    int n = hB ? v - N_NODES : v;
    const u32* Xin = hB ? XinB : XinA;
    const u32* Xprev = hB ? XprevB : XprevA;
    u32* Xout = hB ? XoutB : XoutA;
    const int* rp = hB ? rowptr2 : rowptr1;
    const int2* eg = hB ? edges2 : edges1;

    float acc[8] = {0.f, 0.f, 0.f, 0.f, 0.f, 0.f, 0.f, 0.f};
    gather_sliced(Xin, rp, eg, n, su, l, h, acc);
#pragma unroll
    for (int i = 0; i < 8; i++) acc[i] += __shfl_xor(acc[i], 8, 64);
    if (h) return;

    size_t o = (size_t)n * 256 + su + l * 4;
    if (beta != 0.f) {
        uint4 p = *(const uint4*)(Xprev + o);
        acc[0] = alpha * acc[0] + beta * lo16(p.x); acc[1] = alpha * acc[1] + beta * hi16(p.x);
        acc[2] = alpha * acc[2] + beta * lo16(p.y); acc[3] = alpha * acc[3] + beta * hi16(p.y);
        acc[4] = alpha * acc[4] + beta * lo16(p.z); acc[5] = alpha * acc[5] + beta * hi16(p.z);
        acc[6] = alpha * acc[6] + beta * lo16(p.w); acc[7] = alpha * acc[7] + beta * hi16(p.w);
    } else {
#pragma unroll
        for (int i = 0; i < 8; i++) acc[i] *= alpha;
    }
    uint4 r;
    r.x = pack2(acc[0], acc[1]);
    r.y = pack2(acc[2], acc[3]);
    r.z = pack2(acc[4], acc[5]);
    r.w = pack2(acc[6], acc[7]);
    *(uint4*)(Xout + o) = r;
}

// final: out = -theta * tanh(Q + S1@T1 + S2@T2), fp32 (B,N,64) layout
__global__ __launch_bounds__(256) void spmm_final_kernel(
    const u32* __restrict__ T1, const u32* __restrict__ T2,
    const u32* __restrict__ Q, const u32* __restrict__ theta,
    const int* __restrict__ rowptr1, const int2* __restrict__ edges1,
    const int* __restrict__ rowptr2, const int2* __restrict__ edges2,
    float* __restrict__ outF) {
    int t = threadIdx.x;
    int lane = t & 63;
    int g = lane >> 4;
    int l16 = lane & 15;
    int h = l16 >> 3, l = l16 & 7;
    int slice = blockIdx.x & 7;
    int chunk = blockIdx.x >> 3;           // 625 chunks x 16 rows = 10000 exactly
    int su = slice * 32;
    int n = chunk * 16 + (t >> 6) * 4 + g;

    float acc[8] = {0.f, 0.f, 0.f, 0.f, 0.f, 0.f, 0.f, 0.f};
    gather_sliced(T1, rowptr1, edges1, n, su, l, h, acc);
    gather_sliced(T2, rowptr2, edges2, n, su, l, h, acc);
#pragma unroll
    for (int i = 0; i < 8; i++) acc[i] += __shfl_xor(acc[i], 8, 64);
    if (h) return;

    size_t o = (size_t)n * 256 + su + l * 4;
    uint4 q = *(const uint4*)(Q + o);
    uint4 th = *(const uint4*)(theta + o);
    float res[8];
    res[0] = -lo16(th.x) * fast_tanh(lo16(q.x) + acc[0]);
    res[1] = -hi16(th.x) * fast_tanh(hi16(q.x) + acc[1]);
    res[2] = -lo16(th.y) * fast_tanh(lo16(q.y) + acc[2]);
    res[3] = -hi16(th.y) * fast_tanh(hi16(q.y) + acc[3]);
    res[4] = -lo16(th.z) * fast_tanh(lo16(q.z) + acc[4]);
    res[5] = -hi16(th.z) * fast_tanh(hi16(q.z) + acc[5]);
    res[6] = -lo16(th.w) * fast_tanh(lo16(q.w) + acc[6]);
    res[7] = -hi16(th.w) * fast_tanh(hi16(q.w) + acc[7]);
    // slice == batch index; lane covers features l*8 .. l*8+7
    float* dst = outF + (size_t)slice * (N_NODES * 64) + (size_t)n * 64 + l * 8;
    *(float4*)(dst) = make_float4(res[0], res[1], res[2], res[3]);
    *(float4*)(dst + 4) = make_float4(res[4], res[5], res[6], res[7]);
}

// ---------------- MFMA GEMM: 64 rows/block (4 waves x 16 rows), optional col-split ---
struct Slabs { const u16* p[5]; };

// MODE 0: plain (+bias1 on cols<64) -> 64-wide slabs at O1
// MODE 1: fused: col<64 sigmoid(+bias1)->O1 (64-wide); col>=64 tanh(+bias2)->O2 (128-wide)
template <int FIN, int NM, int NOUT, int NSPLIT, int MODE>
__global__ __launch_bounds__(256) void gemm_kernel(
    Slabs A, const u16* __restrict__ Bp, const float* __restrict__ bias1,
    const float* __restrict__ bias2, u16* __restrict__ O1, u16* __restrict__ O2) {
    constexpr int K = NM * FIN;
    constexpr int KS = K / 32;
    constexpr int CTT = NOUT / 16;
    constexpr int CT = CTT / NSPLIT;
    int lane = threadIdx.x & 63;
    int wave = threadIdx.x >> 6;
    int rowBase = (blockIdx.x / NSPLIT) * 64 + wave * 16;
    int ctBase = (blockIdx.x % NSPLIT) * CT;
    int mrow = lane & 15;
    int kq = lane >> 4;

    float4v acc[CT];
#pragma unroll
    for (int c = 0; c < CT; c++) acc[c] = (float4v){0.f, 0.f, 0.f, 0.f};

#pragma unroll
    for (int ks = 0; ks < KS; ks++) {
        int k = ks * 32 + kq * 8;
        int m = k / FIN;  // uniform within ks
        int koff = k % FIN;
        short8 a = *(const short8*)(A.p[m] + (size_t)(rowBase + mrow) * FIN + koff);
        short8 b[CT];
#pragma unroll
        for (int ct = 0; ct < CT; ct++)
            b[ct] = *(const short8*)(Bp + ((size_t)(ks * CTT + ctBase + ct) * 64 + lane) * 8);
#pragma unroll
        for (int ct = 0; ct < CT; ct++)
            acc[ct] = __builtin_amdgcn_mfma_f32_16x16x32_bf16(a, b[ct], acc[ct], 0, 0, 0);
    }

    int rowq = rowBase + kq * 4;
#pragma unroll
    for (int ct = 0; ct < CT; ct++) {
        int col = (ctBase + ct) * 16 + mrow;
        float bsv;
        if (MODE == 0) bsv = (col < 64) ? bias1[col] : 0.f;
        else bsv = (col < 64) ? bias1[col] : bias2[col - 64];
#pragma unroll
        for (int i = 0; i < 4; i++) {
            float v = acc[ct][i] + bsv;
            int r = rowq + i;
            if (MODE == 0) {
                O1[(size_t)(col >> 6) * SLAB + (size_t)r * 64 + (col & 63)] = f2bf(v);
            } else {
                if (col < 64) {
                    v = 1.f / (1.f + __expf(-v));
                    O1[(size_t)r * 64 + col] = f2bf(v);
                } else {
                    O2[(size_t)r * 128 + (col - 64)] = f2bf(fast_tanh(v));
                }
            }
        }
    }
}

// ---------------- launch ----------------
extern "C" void kernel_launch(void* const* d_in, const int* in_sizes, int n_in,
                              void* d_out, int out_size, void* d_ws, size_t ws_size,
                              hipStream_t stream) {
    const float2* y    = (const float2*)d_in[0];
    const float* W_lat = (const float*)d_in[1];
    const float* b_lat = (const float*)d_in[2];
    const float* W_units = (const float*)d_in[3];
    const float* b_units = (const float*)d_in[4];
    const float* W_final = (const float*)d_in[5];
    const float* sup1w = (const float*)d_in[6];
    const float* sup2w = (const float*)d_in[7];
    const int* rows    = (const int*)d_in[8];
    const int* cols    = (const int*)d_in[9];
    float* out = (float*)d_out;

    char* ws = (char*)d_ws;
    size_t off = 0;
    auto alloc = [&](size_t bytes) -> void* {
        void* p = ws + off;
        off += (bytes + 511) & ~(size_t)511;
        return p;
    };
    int* rowptr1 = (int*)alloc((N_NODES + 1) * 4);
    int* rowptr2 = (int*)alloc((N_NODES + 1) * 4);
    int* cnt = (int*)alloc((size_t)2 * N_NODES * 4);
    int* bsums = (int*)alloc(80 * 4);
    int2* edges1 = (int2*)alloc((size_t)EPAD * 8);
    int2* edges2 = (int2*)alloc((size_t)EPAD * 8);
    u16* bpk12 = (u16*)alloc((size_t)61440 * 2);
    u16* bpkP = (u16*)alloc((size_t)40960 * 2);
    u16* theta = (u16*)alloc((size_t)NB * 64 * 2);
    u16* S = (u16*)alloc((size_t)5 * NB * 64 * 2);  // X-slabs, later Q/P slabs
    u16* H0 = (u16*)alloc((size_t)NB * 128 * 2);
    u16* T1 = (u16*)alloc((size_t)NB * 64 * 2);
    u16* T2 = (u16*)alloc((size_t)NB * 64 * 2);

    hipMemsetAsync(cnt, 0, (size_t)2 * N_NODES * 4, stream);
    // padding slots must be {src=0, w=0.0f}
    hipMemsetAsync(edges1, 0, (size_t)EPAD * 8, stream);
    hipMemsetAsync(edges2, 0, (size_t)EPAD * 8, stream);
    prepcount_kernel<<<11025, 256, 0, stream>>>(y, (u32*)S, W_lat, W_units, bpk12,
                                                W_final, bpkP, rows, cols, cnt);
    blocksum_kernel<<<80, 256, 0, stream>>>(cnt, bsums);
    scanapply_kernel<<<80, 256, 0, stream>>>(cnt, bsums, rowptr1, rowptr2);
    scatter_kernel<<<625, 256, 0, stream>>>(rows, cols, sup1w, sup2w,
                                            cnt, cnt + N_NODES, edges1, edges2);

    // x-side diffusion: X1 = S1@X0, X3 = S2@X0 ; X2 = 2*S1@X1 - X0, X4 = 2*S2@X3 - X0
    const u32* S0 = (const u32*)S;
    u32* X1 = (u32*)(S + 1 * SLAB);
    u32* X2 = (u32*)(S + 2 * SLAB);
    u32* X3 = (u32*)(S + 3 * SLAB);
    u32* X4 = (u32*)(S + 4 * SLAB);
    spmm2_kernel<<<10000, 256, 0, stream>>>(S0, nullptr, X1, S0, nullptr, X3,
                                            rowptr1, edges1, rowptr2, edges2, 1.f, 0.f);
    spmm2_kernel<<<10000, 256, 0, stream>>>(X1, S0, X2, X3, S0, X4,
                                            rowptr1, edges1, rowptr2, edges2, 2.f, -1.f);

    Slabs SX;
    for (int m = 0; m < 5; m++) SX.p[m] = S + (size_t)m * SLAB;
    // fused: theta = sigmoid(X@W_lat + b_lat), H0 = tanh(X@W_units + b_units)
    gemm_kernel<64, 5, 192, 1, 1><<<1250, 256, 0, stream>>>(SX, bpk12, b_lat, b_units, theta, H0);

    // P-GEMM: [Q|P1|P2|P3|P4] = H0 @ bpkP (Q = P0-P2-P4 + b_lat), overlays S
    Slabs SH;
    SH.p[0] = H0;
    gemm_kernel<128, 1, 320, 2, 0><<<2500, 256, 0, stream>>>(SH, bpkP, b_lat, nullptr, S, nullptr);

    const u32* Q  = (const u32*)(S + 0 * SLAB);
    const u32* P1 = (const u32*)(S + 1 * SLAB);
    const u32* P2 = (const u32*)(S + 2 * SLAB);
    const u32* P3 = (const u32*)(S + 3 * SLAB);
    const u32* P4 = (const u32*)(S + 4 * SLAB);
    // T1 = P1 + 2*S1@P2 ; T2 = P3 + 2*S2@P4
    spmm2_kernel<<<10000, 256, 0, stream>>>(P2, P1, (u32*)T1, P4, P3, (u32*)T2,
                                            rowptr1, edges1, rowptr2, edges2, 2.f, 1.f);
    // out = -theta * tanh(Q + S1@T1 + S2@T2)
    spmm_final_kernel<<<5000, 256, 0, stream>>>((const u32*)T1, (const u32*)T2, Q,
                                                (const u32*)theta,
                                                rowptr1, edges1, rowptr2, edges2, out);
}

// Round 6
// 311.479 us; speedup vs baseline: 1.0655x; 1.0655x over previous
//
#include <hip/hip_runtime.h>

#define N_NODES 10000
#define NEDGE 160000
#define NB 80000  /* N_NODES*BATCH */
#define EPAD (NEDGE + 8 * N_NODES) /* padded edge capacity per support */

typedef unsigned int u32;
typedef unsigned short u16;
typedef __attribute__((ext_vector_type(8))) short short8;
typedef __attribute__((ext_vector_type(4))) float float4v;

__device__ __forceinline__ u16 f2bf(float f) {
    u32 u = __float_as_uint(f);
    return (u16)((u + 0x7fffu + ((u >> 16) & 1u)) >> 16);
}
__device__ __forceinline__ float lo16(u32 u) { return __uint_as_float(u << 16); }
__device__ __forceinline__ float hi16(u32 u) { return __uint_as_float(u & 0xffff0000u); }
__device__ __forceinline__ u32 pack2(float a, float b) {
    return (u32)f2bf(a) | (((u32)f2bf(b)) << 16);
}
__device__ __forceinline__ float fast_tanh(float v) {
    return 1.f - 2.f / (__expf(2.f * v) + 1.f);
}

static const size_t SLAB = (size_t)NB * 64;  // u16 elems per 64-wide slab

// ---------------- prep+count: transpose + bpack12 + bpackP + degree count -----------
__global__ __launch_bounds__(256) void prepcount_kernel(
    const float2* __restrict__ y, u32* __restrict__ X0,
    const float* __restrict__ W_lat, const float* __restrict__ W_units,
    u16* __restrict__ bpk12, const float* __restrict__ W_final, u16* __restrict__ bpkP,
    const int* __restrict__ rows, const int* __restrict__ cols, int* __restrict__ cnt) {
    int b = blockIdx.x, t = threadIdx.x;
    if (b < 10000) {
        int idx = b * 256 + t;  // NB*32 outputs exactly
        int fh = idx & 31;
        int rb = idx >> 5;
        int bb = rb & 7;
        int n = rb >> 3;
        float2 v = y[((size_t)bb * N_NODES + n) * 32 + fh];
        X0[idx] = pack2(v.x, v.y);
    } else if (b < 10240) {
        // fused bpack: K=320 (k=m*64+f, wrow=f*5+m), NOUT=192 (0..63 lat, 64..191 units)
        int idx = (b - 10000) * 256 + t;  // < 61440
        int j = idx & 7;
        int lane = (idx >> 3) & 63;
        int rest = idx >> 9;
        int ct = rest % 12;
        int ks = rest / 12;
        int k = ks * 32 + (lane >> 4) * 8 + j;
        int col = ct * 16 + (lane & 15);
        int wrow = (k % 64) * 5 + (k / 64);
        float v = (col < 64) ? W_lat[wrow * 64 + col] : W_units[wrow * 128 + (col - 64)];
        bpk12[idx] = f2bf(v);
    } else if (b < 10400) {
        // bpackP: K=128, NOUT=320; slot0 = W[:,0]-W[:,2]-W[:,4], slot m>=1 = W[:,m]
        int idx = (b - 10240) * 256 + t;  // < 40960
        int j8 = idx & 7;
        int lane = (idx >> 3) & 63;
        int rest = idx >> 9;
        int ct = rest % 20;
        int ks = rest / 20;
        int k = ks * 32 + (lane >> 4) * 8 + j8;
        int col = ct * 16 + (lane & 15);
        int slot = col >> 6, j = col & 63;
        float v;
        if (slot == 0)
            v = W_final[(k * 5 + 0) * 64 + j] - W_final[(k * 5 + 2) * 64 + j] -
                W_final[(k * 5 + 4) * 64 + j];
        else
            v = W_final[(k * 5 + slot) * 64 + j];
        bpkP[idx] = f2bf(v);
    } else {
        int e = (b - 10400) * 256 + t;  // 625*256 == NEDGE exactly
        atomicAdd(&cnt[cols[e]], 1);            // support1: dst=cols
        atomicAdd(&cnt[N_NODES + rows[e]], 1);  // support2: dst=rows
    }
}

// 80 blocks: per-chunk sums of PADDED degrees (rows padded to multiple of 8)
__global__ void blocksum_kernel(const int* __restrict__ cnt, int* __restrict__ bsums) {
    __shared__ int red[4];
    int arr = blockIdx.x / 40;
    int c = blockIdx.x % 40;
    int idx = c * 256 + threadIdx.x;
    int v = (idx < N_NODES) ? ((cnt[arr * N_NODES + idx] + 7) & ~7) : 0;
#pragma unroll
    for (int off = 32; off; off >>= 1) v += __shfl_down(v, off, 64);
    int wv = threadIdx.x >> 6, ln = threadIdx.x & 63;
    if (ln == 0) red[wv] = v;
    __syncthreads();
    if (threadIdx.x == 0) bsums[blockIdx.x] = red[0] + red[1] + red[2] + red[3];
}

// 80 blocks: local scan + serial prefix over chunk sums -> padded rowptr + cursor
__global__ void scanapply_kernel(int* __restrict__ cnt, const int* __restrict__ bsums,
                                 int* __restrict__ rowptr1, int* __restrict__ rowptr2) {
    __shared__ int lds[256];
    int arr = blockIdx.x / 40;
    int c = blockIdx.x % 40;
    int base = 0;
    for (int i = 0; i < c; i++) base += bsums[arr * 40 + i];  // 40-deep serial, L2-hot
    int idx = c * 256 + threadIdx.x;
    bool ok = idx < N_NODES;
    int v = ok ? ((cnt[arr * N_NODES + idx] + 7) & ~7) : 0;
    int t = threadIdx.x;
    lds[t] = v;
    __syncthreads();
    for (int off = 1; off < 256; off <<= 1) {
        int add = (t >= off) ? lds[t - off] : 0;
        __syncthreads();
        lds[t] += add;
        __syncthreads();
    }
    int excl = lds[t] - v + base;
    if (ok) {
        int* rp = arr ? rowptr2 : rowptr1;
        rp[idx] = excl;
        cnt[arr * N_NODES + idx] = excl;  // cursor (actual edges fill from padded start)
    }
    if (c == 39 && t == 255) {
        // grand total (padded) = base + inclusive total of last chunk
        (arr ? rowptr2 : rowptr1)[N_NODES] = base + lds[255];
    }
}

__global__ void scatter_kernel(const int* __restrict__ rows, const int* __restrict__ cols,
                               const float* __restrict__ w1, const float* __restrict__ w2,
                               int* __restrict__ cur1, int* __restrict__ cur2,
                               int2* __restrict__ edges1, int2* __restrict__ edges2) {
    int e = blockIdx.x * 256 + threadIdx.x;
    if (e < NEDGE) {
        int r = rows[e], c = cols[e];
        int p1 = atomicAdd(&cur1[c], 1);
        edges1[p1] = make_int2(r, __float_as_int(w1[e]));
        int p2 = atomicAdd(&cur2[r], 1);
        edges2[p2] = make_int2(c, __float_as_int(w2[e]));
    }
}

// ---------------- SpMM gather: XCD-sliced (batch-slice pinned to one XCD) -----------
// Wave = 8 groups x 8 lanes. Each group owns ONE destination row's 128B batch-slice
// (slice = blockIdx%8 -> round-robins to one XCD). Per-XCD gather working set =
// 2 slabs x 10K x 128B = 2.56 MB -> L2-resident; compulsory L3 fetch drops ~7x.
__device__ __forceinline__ void gacc(float* acc, float w, uint4 u) {
    acc[0] += w * lo16(u.x); acc[1] += w * hi16(u.x);
    acc[2] += w * lo16(u.y); acc[3] += w * hi16(u.y);
    acc[4] += w * lo16(u.z); acc[5] += w * hi16(u.z);
    acc[6] += w * lo16(u.w); acc[7] += w * hi16(u.w);
}

__device__ __forceinline__ void gather_sliced(const u32* __restrict__ Xin,
                                              const int* __restrict__ rp,
                                              const int2* __restrict__ eg,
                                              int row, bool valid, int su, int l,
                                              float* acc) {
    int e = 0, e1 = 0;
    if (valid) {
        e = rp[row] + l;
        e1 = rp[row + 1];
    }
    while (__ballot(e < e1)) {
        int2 me = make_int2(0, 0);
        if (e < e1) me = eg[e];
#pragma unroll
        for (int j = 0; j < 8; j++) {
            int s = __shfl(me.x, j, 8);
            float w = __int_as_float(__shfl(me.y, j, 8));
            uint4 u = *(const uint4*)(Xin + (size_t)s * 256 + su + l * 4);
            gacc(acc, w, u);
        }
        e += 8;
    }
}

__global__ __launch_bounds__(256) void spmm2_kernel(
    const u32* __restrict__ XinA, const u32* __restrict__ XprevA, u32* __restrict__ XoutA,
    const u32* __restrict__ XinB, const u32* __restrict__ XprevB, u32* __restrict__ XoutB,
    const int* __restrict__ rowptr1, const int2* __restrict__ edges1,
    const int* __restrict__ rowptr2, const int2* __restrict__ edges2,
    float alpha, float beta) {
    int t = threadIdx.x;
    int lane = t & 63;
    int g = lane >> 3, l = lane & 7;
    int slice = blockIdx.x & 7;          // -> XCD (round-robin dispatch)
    int chunk = blockIdx.x >> 3;
    int su = slice * 32;                 // u32 offset of this batch-slice in a row
    int v = chunk * 32 + (t >> 6) * 8 + g;  // 0..19999 (20000 % 32 == 0)
    bool hB = v >= N_NODES;
    int n = hB ? v - N_NODES : v;
    const u32* Xin = hB ? XinB : XinA;
    const u32* Xprev = hB ? XprevB : XprevA;
    u32* Xout = hB ? XoutB : XoutA;
    const int* rp = hB ? rowptr2 : rowptr1;
    const int2* eg = hB ? edges2 : edges1;

    float acc[8] = {0.f, 0.f, 0.f, 0.f, 0.f, 0.f, 0.f, 0.f};
    gather_sliced(Xin, rp, eg, n, true, su, l, acc);

    size_t o = (size_t)n * 256 + su + l * 4;
    if (beta != 0.f) {
        uint4 p = *(const uint4*)(Xprev + o);
        acc[0] = alpha * acc[0] + beta * lo16(p.x); acc[1] = alpha * acc[1] + beta * hi16(p.x);
        acc[2] = alpha * acc[2] + beta * lo16(p.y); acc[3] = alpha * acc[3] + beta * hi16(p.y);
        acc[4] = alpha * acc[4] + beta * lo16(p.z); acc[5] = alpha * acc[5] + beta * hi16(p.z);
        acc[6] = alpha * acc[6] + beta * lo16(p.w); acc[7] = alpha * acc[7] + beta * hi16(p.w);
    } else {
#pragma unroll
        for (int i = 0; i < 8; i++) acc[i] *= alpha;
    }
    uint4 r;
    r.x = pack2(acc[0], acc[1]);
    r.y = pack2(acc[2], acc[3]);
    r.z = pack2(acc[4], acc[5]);
    r.w = pack2(acc[6], acc[7]);
    *(uint4*)(Xout + o) = r;
}

// final: out = -theta * tanh(Q + S1@T1 + S2@T2), fp32 (B,N,64) layout
__global__ __launch_bounds__(256) void spmm_final_kernel(
    const u32* __restrict__ T1, const u32* __restrict__ T2,
    const u32* __restrict__ Q, const u32* __restrict__ theta,
    const int* __restrict__ rowptr1, const int2* __restrict__ edges1,
    const int* __restrict__ rowptr2, const int2* __restrict__ edges2,
    float* __restrict__ outF) {
    int t = threadIdx.x;
    int lane = t & 63;
    int g = lane >> 3, l = lane & 7;
    int slice = blockIdx.x & 7;
    int chunk = blockIdx.x >> 3;
    int su = slice * 32;
    int n = chunk * 32 + (t >> 6) * 8 + g;
    bool valid = n < N_NODES;

    float acc[8] = {0.f, 0.f, 0.f, 0.f, 0.f, 0.f, 0.f, 0.f};
    gather_sliced(T1, rowptr1, edges1, n, valid, su, l, acc);
    gather_sliced(T2, rowptr2, edges2, n, valid, su, l, acc);
    if (!valid) return;

    size_t o = (size_t)n * 256 + su + l * 4;
    uint4 q = *(const uint4*)(Q + o);
    uint4 th = *(const uint4*)(theta + o);
    float res[8];
    res[0] = -lo16(th.x) * fast_tanh(lo16(q.x) + acc[0]);
    res[1] = -hi16(th.x) * fast_tanh(hi16(q.x) + acc[1]);
    res[2] = -lo16(th.y) * fast_tanh(lo16(q.y) + acc[2]);
    res[3] = -hi16(th.y) * fast_tanh(hi16(q.y) + acc[3]);
    res[4] = -lo16(th.z) * fast_tanh(lo16(q.z) + acc[4]);
    res[5] = -hi16(th.z) * fast_tanh(hi16(q.z) + acc[5]);
    res[6] = -lo16(th.w) * fast_tanh(lo16(q.w) + acc[6]);
    res[7] = -hi16(th.w) * fast_tanh(hi16(q.w) + acc[7]);
    // slice == batch index; lane covers features l*8 .. l*8+7
    float* dst = outF + (size_t)slice * (N_NODES * 64) + (size_t)n * 64 + l * 8;
    *(float4*)(dst) = make_float4(res[0], res[1], res[2], res[3]);
    *(float4*)(dst + 4) = make_float4(res[4], res[5], res[6], res[7]);
}

// ---------------- MFMA GEMM: 8 waves x 16 rows = 128 rows/block, B-half in LDS -----
// Each block covers a column half (NSPLIT=2). The B column-half (KS x CT x 1KB tiles)
// is staged to LDS once per block, then all 8 waves read fragments via ds_read_b128.
// This removes the per-wave redundant B reload from L2 (was 120KB/wave -> 600MB total).
struct Slabs { const u16* p[5]; };

// MODE 0: plain (+bias1 on cols<64) -> 64-wide slabs at O1
// MODE 1: fused: col<64 sigmoid(+bias1)->O1 (64-wide); col>=64 tanh(+bias2)->O2 (128-wide)
template <int FIN, int NM, int NOUT, int NSPLIT, int MODE>
__global__ __launch_bounds__(512) void gemm_kernel(
    Slabs A, const u16* __restrict__ Bp, const float* __restrict__ bias1,
    const float* __restrict__ bias2, u16* __restrict__ O1, u16* __restrict__ O2) {
    constexpr int K = NM * FIN;
    constexpr int KS = K / 32;
    constexpr int CTT = NOUT / 16;
    constexpr int CT = CTT / NSPLIT;
    __shared__ u16 Blds[KS * CT * 64 * 8];  // KS x CT x 1KB tiles

    int t = threadIdx.x;
    int lane = t & 63;
    int wave = t >> 6;  // 0..7
    int rowBase = (blockIdx.x / NSPLIT) * 128 + wave * 16;
    int ctBase = (blockIdx.x % NSPLIT) * CT;
    int mrow = lane & 15;
    int kq = lane >> 4;

    // stage B column-half: tile (ks,ct) from Bp[(ks*CTT + ctBase + ct)*64*8]
    for (int idx = t; idx < KS * CT * 64; idx += 512) {
        int bl = idx & 63;
        int ct = (idx >> 6) % CT;
        int ks = idx / (64 * CT);
        *(uint4*)(Blds + (size_t)idx * 8) =
            *(const uint4*)(Bp + ((size_t)(ks * CTT + ctBase + ct) * 64 + bl) * 8);
    }
    __syncthreads();

    float4v acc[CT];
#pragma unroll
    for (int c = 0; c < CT; c++) acc[c] = (float4v){0.f, 0.f, 0.f, 0.f};

#pragma unroll
    for (int ks = 0; ks < KS; ks++) {
        int k = ks * 32 + kq * 8;
        int m = k / FIN;  // uniform within ks
        int koff = k % FIN;
        short8 a = *(const short8*)(A.p[m] + (size_t)(rowBase + mrow) * FIN + koff);
#pragma unroll
        for (int ct = 0; ct < CT; ct++) {
            short8 b = *(const short8*)(Blds + ((size_t)(ks * CT + ct) * 64 + lane) * 8);
            acc[ct] = __builtin_amdgcn_mfma_f32_16x16x32_bf16(a, b, acc[ct], 0, 0, 0);
        }
    }

    int rowq = rowBase + kq * 4;
#pragma unroll
    for (int ct = 0; ct < CT; ct++) {
        int col = (ctBase + ct) * 16 + mrow;
        float bsv;
        if (MODE == 0) bsv = (col < 64) ? bias1[col] : 0.f;
        else bsv = (col < 64) ? bias1[col] : bias2[col - 64];
#pragma unroll
        for (int i = 0; i < 4; i++) {
            float v = acc[ct][i] + bsv;
            int r = rowq + i;
            if (MODE == 0) {
                O1[(size_t)(col >> 6) * SLAB + (size_t)r * 64 + (col & 63)] = f2bf(v);
            } else {
                if (col < 64) {
                    v = 1.f / (1.f + __expf(-v));
                    O1[(size_t)r * 64 + col] = f2bf(v);
                } else {
                    O2[(size_t)r * 128 + (col - 64)] = f2bf(fast_tanh(v));
                }
            }
        }
    }
}

// ---------------- launch ----------------
extern "C" void kernel_launch(void* const* d_in, const int* in_sizes, int n_in,
                              void* d_out, int out_size, void* d_ws, size_t ws_size,
                              hipStream_t stream) {
    const float2* y    = (const float2*)d_in[0];
    const float* W_lat = (const float*)d_in[1];
    const float* b_lat = (const float*)d_in[2];
    const float* W_units = (const float*)d_in[3];
    const float* b_units = (const float*)d_in[4];
    const float* W_final = (const float*)d_in[5];
    const float* sup1w = (const float*)d_in[6];
    const float* sup2w = (const float*)d_in[7];
    const int* rows    = (const int*)d_in[8];
    const int* cols    = (const int*)d_in[9];
    float* out = (float*)d_out;

    char* ws = (char*)d_ws;
    size_t off = 0;
    auto alloc = [&](size_t bytes) -> void* {
        void* p = ws + off;
        off += (bytes + 511) & ~(size_t)511;
        return p;
    };
    int* rowptr1 = (int*)alloc((N_NODES + 1) * 4);
    int* rowptr2 = (int*)alloc((N_NODES + 1) * 4);
    int* cnt = (int*)alloc((size_t)2 * N_NODES * 4);
    int* bsums = (int*)alloc(80 * 4);
    int2* edges1 = (int2*)alloc((size_t)EPAD * 8);
    int2* edges2 = (int2*)alloc((size_t)EPAD * 8);
    u16* bpk12 = (u16*)alloc((size_t)61440 * 2);
    u16* bpkP = (u16*)alloc((size_t)40960 * 2);
    u16* theta = (u16*)alloc((size_t)NB * 64 * 2);
    u16* S = (u16*)alloc((size_t)5 * NB * 64 * 2);  // X-slabs, later Q/P slabs
    u16* H0 = (u16*)alloc((size_t)NB * 128 * 2);
    u16* T1 = (u16*)alloc((size_t)NB * 64 * 2);
    u16* T2 = (u16*)alloc((size_t)NB * 64 * 2);

    hipMemsetAsync(cnt, 0, (size_t)2 * N_NODES * 4, stream);
    // padding slots must be {src=0, w=0.0f}
    hipMemsetAsync(edges1, 0, (size_t)EPAD * 8, stream);
    hipMemsetAsync(edges2, 0, (size_t)EPAD * 8, stream);
    prepcount_kernel<<<11025, 256, 0, stream>>>(y, (u32*)S, W_lat, W_units, bpk12,
                                                W_final, bpkP, rows, cols, cnt);
    blocksum_kernel<<<80, 256, 0, stream>>>(cnt, bsums);
    scanapply_kernel<<<80, 256, 0, stream>>>(cnt, bsums, rowptr1, rowptr2);
    scatter_kernel<<<625, 256, 0, stream>>>(rows, cols, sup1w, sup2w,
                                            cnt, cnt + N_NODES, edges1, edges2);

    // x-side diffusion: X1 = S1@X0, X3 = S2@X0 ; X2 = 2*S1@X1 - X0, X4 = 2*S2@X3 - X0
    const u32* S0 = (const u32*)S;
    u32* X1 = (u32*)(S + 1 * SLAB);
    u32* X2 = (u32*)(S + 2 * SLAB);
    u32* X3 = (u32*)(S + 3 * SLAB);
    u32* X4 = (u32*)(S + 4 * SLAB);
    spmm2_kernel<<<5000, 256, 0, stream>>>(S0, nullptr, X1, S0, nullptr, X3,
                                           rowptr1, edges1, rowptr2, edges2, 1.f, 0.f);
    spmm2_kernel<<<5000, 256, 0, stream>>>(X1, S0, X2, X3, S0, X4,
                                           rowptr1, edges1, rowptr2, edges2, 2.f, -1.f);

    Slabs SX;
    for (int m = 0; m < 5; m++) SX.p[m] = S + (size_t)m * SLAB;
    // fused: theta = sigmoid(X@W_lat + b_lat), H0 = tanh(X@W_units + b_units)
    gemm_kernel<64, 5, 192, 2, 1><<<1250, 512, 0, stream>>>(SX, bpk12, b_lat, b_units, theta, H0);

    // P-GEMM: [Q|P1|P2|P3|P4] = H0 @ bpkP (Q = P0-P2-P4 + b_lat), overlays S
    Slabs SH;
    SH.p[0] = H0;
    gemm_kernel<128, 1, 320, 2, 0><<<1250, 512, 0, stream>>>(SH, bpkP, b_lat, nullptr, S, nullptr);

    const u32* Q  = (const u32*)(S + 0 * SLAB);
    const u32* P1 = (const u32*)(S + 1 * SLAB);
    const u32* P2 = (const u32*)(S + 2 * SLAB);
    const u32* P3 = (const u32*)(S + 3 * SLAB);
    const u32* P4 = (const u32*)(S + 4 * SLAB);
    // T1 = P1 + 2*S1@P2 ; T2 = P3 + 2*S2@P4
    spmm2_kernel<<<5000, 256, 0, stream>>>(P2, P1, (u32*)T1, P4, P3, (u32*)T2,
                                           rowptr1, edges1, rowptr2, edges2, 2.f, 1.f);
    // out = -theta * tanh(Q + S1@T1 + S2@T2)
    spmm_final_kernel<<<2504, 256, 0, stream>>>((const u32*)T1, (const u32*)T2, Q,
                                                (const u32*)theta,
                                                rowptr1, edges1, rowptr2, edges2, out);
}